// Round 1
// baseline (1246.257 us; speedup 1.0000x reference)
//
#include <hip/hip_runtime.h>
#include <hip/hip_bf16.h>

typedef unsigned int u32;

#define SCAN_CHUNK 1024

__device__ __forceinline__ float log_sigmoid(float x) {
    return fminf(x, 0.f) - log1pf(expf(-fabsf(x)));
}

// f(n,d) = (emb + h1 + h2)/3 computed on the fly
__device__ __forceinline__ float fval(const float* __restrict__ e,
                                      const float* __restrict__ h1,
                                      const float* __restrict__ h2,
                                      int n, int l) {
    size_t idx = (size_t)n * 64 + l;
    return (e[idx] + h1[idx] + h2[idx]) * (1.f / 3.f);
}

// ---------------- degree histogram ----------------
__global__ void k_hist(const int* __restrict__ dst, u32* __restrict__ deg, int E) {
    int stride = gridDim.x * blockDim.x;
    for (int e = blockIdx.x * blockDim.x + threadIdx.x; e < E; e += stride)
        atomicAdd(&deg[dst[e]], 1u);
}

// ---------------- prefix scan (3 phases) ----------------
__global__ void k_scan1(const u32* __restrict__ deg, u32* __restrict__ bsum, int N) {
    __shared__ u32 lds[256];
    int base = blockIdx.x * SCAN_CHUNK + threadIdx.x * 4;
    u32 s = 0;
#pragma unroll
    for (int i = 0; i < 4; ++i) { int n = base + i; if (n < N) s += deg[n]; }
    lds[threadIdx.x] = s; __syncthreads();
    for (int off = 128; off > 0; off >>= 1) {
        if (threadIdx.x < off) lds[threadIdx.x] += lds[threadIdx.x + off];
        __syncthreads();
    }
    if (threadIdx.x == 0) bsum[blockIdx.x] = lds[0];
}

__global__ void k_scan2(u32* bsum, int nb, u32* rowstart, int N, u32 E) {
    if (threadIdx.x == 0 && blockIdx.x == 0) {
        u32 run = 0;
        for (int i = 0; i < nb; ++i) { u32 v = bsum[i]; bsum[i] = run; run += v; }
        rowstart[N] = E;
    }
}

__global__ void k_scan3(const u32* __restrict__ deg, const u32* __restrict__ bsum,
                        u32* __restrict__ rowstart, u32* __restrict__ fillc, int N) {
    __shared__ u32 lds[256];
    int t = threadIdx.x;
    int base = blockIdx.x * SCAN_CHUNK + t * 4;
    u32 v[4]; u32 s = 0;
#pragma unroll
    for (int i = 0; i < 4; ++i) { int n = base + i; v[i] = (n < N) ? deg[n] : 0u; s += v[i]; }
    lds[t] = s; __syncthreads();
    for (int off = 1; off < 256; off <<= 1) {
        u32 x = (t >= off) ? lds[t - off] : 0u;
        __syncthreads();
        lds[t] += x;
        __syncthreads();
    }
    u32 excl = lds[t] - s + bsum[blockIdx.x];
#pragma unroll
    for (int i = 0; i < 4; ++i) {
        int n = base + i;
        if (n < N) { rowstart[n] = excl; fillc[n] = excl; }
        excl += v[i];
    }
}

__global__ void k_csrfill(const int* __restrict__ src, const int* __restrict__ dst,
                          u32* __restrict__ fillc, int* __restrict__ csr, int E) {
    int stride = gridDim.x * blockDim.x;
    for (int e = blockIdx.x * blockDim.x + threadIdx.x; e < E; e += stride) {
        u32 pos = atomicAdd(&fillc[dst[e]], 1u);
        csr[pos] = src[e];
    }
}

__global__ void k_norm(const u32* __restrict__ deg, float* __restrict__ norm, int N) {
    int stride = gridDim.x * blockDim.x;
    for (int n = blockIdx.x * blockDim.x + threadIdx.x; n < N; n += stride)
        norm[n] = rsqrtf(fmaxf((float)deg[n], 1.f));
}

// ---------------- mask dtype detection (bool-as-uint8 vs int32) ----------------
__global__ void k_mask_detect(const int* __restrict__ m, int* flag) {
    __shared__ int allok;
    if (threadIdx.x == 0) allok = 1;
    __syncthreads();
    bool ok = true;
    for (int i = threadIdx.x; i < 1024; i += blockDim.x) {
        int v = m[i];
        if (v != 0 && v != 1) ok = false;
    }
    if (!ok) allok = 0;
    __syncthreads();
    if (threadIdx.x == 0) flag[0] = allok;   // 1 => int32 mask, 0 => byte mask
}

// ---------------- propagation: wave per node, lane per dim, both tables ----------------
__global__ void k_pull(const float* __restrict__ inI, const float* __restrict__ inP,
                       float* __restrict__ outI, float* __restrict__ outP,
                       const int* __restrict__ csr, const u32* __restrict__ rowstart,
                       const float* __restrict__ norm, int N) {
    int lane = threadIdx.x & 63;
    int wid = (blockIdx.x * blockDim.x + threadIdx.x) >> 6;
    int nw = (gridDim.x * blockDim.x) >> 6;
    for (int n = wid; n < N; n += nw) {
        u32 s0 = rowstart[n], s1 = rowstart[n + 1];
        float accI = 0.f, accP = 0.f;
        for (u32 e0 = s0; e0 < s1; e0 += 64) {
            int cnt = (int)min(64u, s1 - e0);
            int sidx = 0; float ns = 0.f;
            if (lane < cnt) { sidx = csr[e0 + lane]; ns = norm[sidx]; }
            for (int j = 0; j < cnt; ++j) {
                int sj = __shfl(sidx, j);
                float nj = __shfl(ns, j);
                accI = fmaf(nj, inI[(size_t)sj * 64 + lane], accI);
                accP = fmaf(nj, inP[(size_t)sj * 64 + lane], accP);
            }
        }
        float nn = norm[n];
        outI[(size_t)n * 64 + lane] = accI * nn;
        outP[(size_t)n * 64 + lane] = accP * nn;
    }
}

// ---------------- indicator build ----------------
__global__ void k_ind(const int* __restrict__ user, const int* __restrict__ itp,
                      const int* __restrict__ itn,
                      float* __restrict__ item_ind, float* __restrict__ user_ind,
                      int B, int NUSER) {
    int stride = gridDim.x * blockDim.x;
    for (int b = blockIdx.x * blockDim.x + threadIdx.x; b < B; b += stride) {
        item_ind[itp[b] + NUSER] = 1.f;
        item_ind[itn[b] + NUSER] = 1.f;
        user_ind[user[b]] = 1.f;
    }
}

// ---------------- batched BPR-style losses: wave per batch row ----------------
__global__ void k_loss(const float* __restrict__ eI, const float* __restrict__ h1I, const float* __restrict__ h2I,
                       const float* __restrict__ eP, const float* __restrict__ h1P, const float* __restrict__ h2P,
                       const int* __restrict__ user, const int* __restrict__ itp, const int* __restrict__ itn,
                       const void* __restrict__ maskp, const int* __restrict__ flag,
                       float* __restrict__ acc, int B, int NUSER) {
    int lane = threadIdx.x & 63;
    int wib = threadIdx.x >> 6;
    int b = (blockIdx.x * blockDim.x + threadIdx.x) >> 6;
    __shared__ float part[4][3];
    float r0 = 0.f, r1 = 0.f, r2 = 0.f;
    if (b < B) {
        int u = user[b];
        int ip = itp[b] + NUSER;
        int in_ = itn[b] + NUSER;
        float uI = fval(eI, h1I, h2I, u, lane);
        float pI = fval(eI, h1I, h2I, ip, lane);
        float nI = fval(eI, h1I, h2I, in_, lane);
        float uP = fval(eP, h1P, h2P, u, lane);
        float pP = fval(eP, h1P, h2P, ip, lane);
        float nP = fval(eP, h1P, h2P, in_, lane);
        float dpI = uI * pI, dnI = uI * nI, dpP = uP * pP, dnP = uP * nP;
        for (int off = 32; off > 0; off >>= 1) {
            dpI += __shfl_xor(dpI, off);
            dnI += __shfl_xor(dnI, off);
            dpP += __shfl_xor(dpP, off);
            dnP += __shfl_xor(dnP, off);
        }
        if (lane == 0) {
            float m = (*flag) ? (float)(((const int*)maskp)[b] != 0)
                              : (float)(((const unsigned char*)maskp)[b] != 0);
            r0 = log_sigmoid(dpI + dpP - dnI - dnP);
            r1 = m * log_sigmoid(dpI - dnI);
            r2 = m * log_sigmoid(dnP - dpP) + (1.f - m) * log_sigmoid(dpP - dnP);
        }
    }
    if (lane == 0) { part[wib][0] = r0; part[wib][1] = r1; part[wib][2] = r2; }
    __syncthreads();
    if (threadIdx.x == 0) {
        float s0 = 0.f, s1 = 0.f, s2 = 0.f;
        for (int w = 0; w < 4; ++w) { s0 += part[w][0]; s1 += part[w][1]; s2 += part[w][2]; }
        atomicAdd(&acc[0], s0); atomicAdd(&acc[1], s1); atomicAdd(&acc[2], s2);
    }
}

// ---------------- discrepancy reduction: wave per node ----------------
__global__ void k_disc(const float* __restrict__ eI, const float* __restrict__ h1I, const float* __restrict__ h2I,
                       const float* __restrict__ eP, const float* __restrict__ h1P, const float* __restrict__ h2P,
                       const float* __restrict__ item_ind, const float* __restrict__ user_ind,
                       float* __restrict__ acc, int N) {
    int lane = threadIdx.x & 63;
    int wib = threadIdx.x >> 6;
    int wid = (blockIdx.x * blockDim.x + threadIdx.x) >> 6;
    int nw = (gridDim.x * blockDim.x) >> 6;
    float sI = 0.f, sU = 0.f, cI = 0.f, cU = 0.f;
    for (int n = wid; n < N; n += nw) {
        float d = fval(eI, h1I, h2I, n, lane) - fval(eP, h1P, h2P, n, lane);
        float d2 = d * d;
        float ii = item_ind[n], ui = user_ind[n];
        sI += ii * d2; sU += ui * d2;
        if (lane == 0) { cI += ii; cU += ui; }
    }
    for (int off = 32; off > 0; off >>= 1) { sI += __shfl_xor(sI, off); sU += __shfl_xor(sU, off); }
    __shared__ float part[4][4];
    if (lane == 0) { part[wib][0] = sI; part[wib][1] = cI; part[wib][2] = sU; part[wib][3] = cU; }
    __syncthreads();
    if (threadIdx.x == 0) {
        float a = 0.f, b = 0.f, c = 0.f, d = 0.f;
        for (int w = 0; w < 4; ++w) { a += part[w][0]; b += part[w][1]; c += part[w][2]; d += part[w][3]; }
        atomicAdd(&acc[3], a); atomicAdd(&acc[4], b); atomicAdd(&acc[5], c); atomicAdd(&acc[6], d);
    }
}

__global__ void k_final(const float* __restrict__ acc, float* __restrict__ out, int B) {
    if (threadIdx.x == 0 && blockIdx.x == 0) {
        float invB = 1.f / (float)B;
        out[0] = -acc[0] * invB;
        out[1] = -0.1f * acc[1] * invB;
        out[2] = -0.1f * acc[2] * invB;
        float disc = acc[3] / (fmaxf(acc[4], 1.f) * 64.f) + acc[5] / (fmaxf(acc[6], 1.f) * 64.f);
        out[3] = -0.01f * disc;
    }
}

extern "C" void kernel_launch(void* const* d_in, const int* in_sizes, int n_in,
                              void* d_out, int out_size, void* d_ws, size_t ws_size,
                              hipStream_t stream) {
    const float* emb_int = (const float*)d_in[0];
    const float* emb_pop = (const float*)d_in[1];
    const int* user   = (const int*)d_in[2];
    const int* item_p = (const int*)d_in[3];
    const int* item_n = (const int*)d_in[4];
    const void* mask  = d_in[5];
    const int* src    = (const int*)d_in[6];
    const int* dst    = (const int*)d_in[7];

    const int D = 64;
    const int N = in_sizes[0] / D;   // 150000
    const int B = in_sizes[2];       // 4096
    const int E = in_sizes[6];       // 4000000
    const int NUSER = 100000;

    char* ws = (char*)d_ws;
    size_t off = 0;
    auto take = [&](size_t bytes) -> void* {
        void* p = ws + off;
        off += (bytes + 255) & ~(size_t)255;
        return p;
    };
    u32*   deg      = (u32*)take((size_t)N * 4);
    float* acc      = (float*)take(256);            // acc[0..6]; flag at acc[15]
    float* item_ind = (float*)take((size_t)N * 4);
    float* user_ind = (float*)take((size_t)N * 4);
    size_t zero_bytes = off;                         // contiguous region to zero each call
    float* norm     = (float*)take((size_t)N * 4);
    u32*   rowstart = (u32*)take((size_t)(N + 1) * 4);
    u32*   fillc    = (u32*)take((size_t)N * 4);
    int*   csr      = (int*)take((size_t)E * 4);
    u32*   bsum     = (u32*)take(4096);
    float* h1I      = (float*)take((size_t)N * D * 4);
    float* h1P      = (float*)take((size_t)N * D * 4);
    float* h2I      = (float*)take((size_t)N * D * 4);
    float* h2P      = (float*)take((size_t)N * D * 4);
    int* flag = (int*)acc + 15;

    hipMemsetAsync(d_ws, 0, zero_bytes, stream);

    k_hist<<<2048, 256, 0, stream>>>(dst, deg, E);
    int nbScan = (N + SCAN_CHUNK - 1) / SCAN_CHUNK;
    k_scan1<<<nbScan, 256, 0, stream>>>(deg, bsum, N);
    k_scan2<<<1, 64, 0, stream>>>(bsum, nbScan, rowstart, N, (u32)E);
    k_scan3<<<nbScan, 256, 0, stream>>>(deg, bsum, rowstart, fillc, N);
    k_csrfill<<<2048, 256, 0, stream>>>(src, dst, fillc, csr, E);
    k_norm<<<(N + 255) / 256, 256, 0, stream>>>(deg, norm, N);
    k_mask_detect<<<1, 256, 0, stream>>>((const int*)mask, flag);

    // layer 1: h1 = norm .* (A (norm .* emb))
    k_pull<<<2048, 256, 0, stream>>>(emb_int, emb_pop, h1I, h1P, csr, rowstart, norm, N);
    // layer 2: h2 = norm .* (A (norm .* h1))
    k_pull<<<2048, 256, 0, stream>>>(h1I, h1P, h2I, h2P, csr, rowstart, norm, N);

    k_ind<<<64, 256, 0, stream>>>(user, item_p, item_n, item_ind, user_ind, B, NUSER);
    k_loss<<<(B * 64 + 255) / 256, 256, 0, stream>>>(emb_int, h1I, h2I, emb_pop, h1P, h2P,
                                                     user, item_p, item_n, mask, flag, acc, B, NUSER);
    k_disc<<<512, 256, 0, stream>>>(emb_int, h1I, h2I, emb_pop, h1P, h2P,
                                    item_ind, user_ind, acc, N);
    k_final<<<1, 64, 0, stream>>>(acc, (float*)d_out, B);
}

// Round 2
// 871.287 us; speedup vs baseline: 1.4304x; 1.4304x over previous
//
#include <hip/hip_runtime.h>
#include <hip/hip_bf16.h>

typedef unsigned int u32;

#define KNODES 512
#define KSHIFT 9
#define NBMAX 1024
#define CHUNK 4096

__device__ __forceinline__ float log_sigmoid(float x) {
    return fminf(x, 0.f) - log1pf(expf(-fabsf(x)));
}

__device__ __forceinline__ float fval(const float* __restrict__ e,
                                      const float* __restrict__ h1,
                                      const float* __restrict__ h2,
                                      int n, int l) {
    size_t idx = (size_t)n * 64 + l;
    return (e[idx] + h1[idx] + h2[idx]) * (1.f / 3.f);
}

// ---------------- bucket histogram (buckets of 512 nodes) ----------------
__global__ void k_bhist(const int* __restrict__ dst, u32* __restrict__ bcnt, int E, int nb) {
    __shared__ u32 h[NBMAX];
    for (int i = threadIdx.x; i < nb; i += blockDim.x) h[i] = 0;
    __syncthreads();
    int stride = gridDim.x * blockDim.x;
    for (int e = blockIdx.x * blockDim.x + threadIdx.x; e < E; e += stride)
        atomicAdd(&h[((u32)dst[e]) >> KSHIFT], 1u);
    __syncthreads();
    for (int i = threadIdx.x; i < nb; i += blockDim.x)
        if (h[i]) atomicAdd(&bcnt[i], h[i]);
}

// ---------------- bucket scan (tiny) ----------------
__global__ void k_bscan(const u32* __restrict__ bcnt, u32* __restrict__ bstart,
                        u32* __restrict__ bfill, int nb, u32 E,
                        u32* __restrict__ rowstart, int N) {
    if (threadIdx.x == 0 && blockIdx.x == 0) {
        u32 run = 0;
        for (int i = 0; i < nb; ++i) { bstart[i] = run; bfill[i] = run; run += bcnt[i]; }
        bstart[nb] = run;
        rowstart[N] = E;
    }
}

// ---------------- scatter edges into bucket-contiguous packed array ----------------
// pack = (local_dst[9b] << 18) | src[18b]
__global__ void k_bscatter(const int* __restrict__ src, const int* __restrict__ dst,
                           u32* __restrict__ bfill, u32* __restrict__ packed, int E, int nb) {
    __shared__ u32 h[NBMAX];
    const int t = threadIdx.x;
    const int base = blockIdx.x * CHUNK;
    const int PT = CHUNK / 256; // 16
    u32 dv[PT], sv[PT];
#pragma unroll
    for (int i = 0; i < PT; ++i) {
        int e = base + t + i * 256;
        if (e < E) { dv[i] = (u32)dst[e]; sv[i] = (u32)src[e]; }
        else dv[i] = 0xFFFFFFFFu;
    }
    for (int i = t; i < nb; i += 256) h[i] = 0;
    __syncthreads();
#pragma unroll
    for (int i = 0; i < PT; ++i)
        if (dv[i] != 0xFFFFFFFFu) atomicAdd(&h[dv[i] >> KSHIFT], 1u);
    __syncthreads();
    for (int i = t; i < nb; i += 256) {
        u32 c = h[i];
        h[i] = c ? atomicAdd(&bfill[i], c) : 0u;
    }
    __syncthreads();
#pragma unroll
    for (int i = 0; i < PT; ++i) {
        if (dv[i] != 0xFFFFFFFFu) {
            u32 b = dv[i] >> KSHIFT;
            u32 pos = atomicAdd(&h[b], 1u);
            packed[pos] = ((dv[i] & (KNODES - 1)) << 18) | sv[i];
        }
    }
}

// ---------------- per-bucket CSR build: deg, rowstart, norm, csr ----------------
__global__ void k_bbuild(const u32* __restrict__ packed, const u32* __restrict__ bstart,
                         u32* __restrict__ rowstart, float* __restrict__ norm,
                         int* __restrict__ csr, int N) {
    __shared__ u32 deg[KNODES], fill[KNODES], s256[256];
    const int t = threadIdx.x;
    const int bkt = blockIdx.x;
    const int nodeBase = bkt << KSHIFT;
    u32 e0 = bstart[bkt], e1 = bstart[bkt + 1];
    deg[t] = 0; deg[t + 256] = 0;
    __syncthreads();
    for (u32 e = e0 + t; e < e1; e += 256)
        atomicAdd(&deg[packed[e] >> 18], 1u);
    __syncthreads();
    u32 a = deg[2 * t], b = deg[2 * t + 1];
    s256[t] = a + b;
    __syncthreads();
    for (int off = 1; off < 256; off <<= 1) {
        u32 x = (t >= off) ? s256[t - off] : 0u;
        __syncthreads();
        s256[t] += x;
        __syncthreads();
    }
    u32 ebase = (t ? s256[t - 1] : 0u);
    fill[2 * t] = ebase;
    fill[2 * t + 1] = ebase + a;
    int n0 = nodeBase + 2 * t, n1 = nodeBase + 2 * t + 1;
    if (n0 < N) { rowstart[n0] = e0 + ebase;     norm[n0] = rsqrtf(fmaxf((float)a, 1.f)); }
    if (n1 < N) { rowstart[n1] = e0 + ebase + a; norm[n1] = rsqrtf(fmaxf((float)b, 1.f)); }
    __syncthreads();
    for (u32 e = e0 + t; e < e1; e += 256) {
        u32 p = packed[e];
        u32 ln = p >> 18;
        u32 pos = atomicAdd(&fill[ln], 1u);
        csr[e0 + pos] = (int)(p & 0x3FFFFu);
    }
}

// ---------------- mask dtype detection (bool-as-uint8 vs int32) ----------------
__global__ void k_mask_detect(const int* __restrict__ m, int* flag) {
    __shared__ int allok;
    if (threadIdx.x == 0) allok = 1;
    __syncthreads();
    bool ok = true;
    for (int i = threadIdx.x; i < 1024; i += blockDim.x) {
        int v = m[i];
        if (v != 0 && v != 1) ok = false;
    }
    if (!ok) allok = 0;
    __syncthreads();
    if (threadIdx.x == 0) flag[0] = allok;   // 1 => int32 mask, 0 => byte mask
}

// ---------------- propagation: wave per node, lane per dim, both tables ----------------
__global__ void k_pull(const float* __restrict__ inI, const float* __restrict__ inP,
                       float* __restrict__ outI, float* __restrict__ outP,
                       const int* __restrict__ csr, const u32* __restrict__ rowstart,
                       const float* __restrict__ norm, int N) {
    int lane = threadIdx.x & 63;
    int wid = (blockIdx.x * blockDim.x + threadIdx.x) >> 6;
    int nw = (gridDim.x * blockDim.x) >> 6;
    for (int n = wid; n < N; n += nw) {
        u32 s0 = rowstart[n], s1 = rowstart[n + 1];
        float accI = 0.f, accP = 0.f;
        for (u32 e0 = s0; e0 < s1; e0 += 64) {
            int cnt = (int)min(64u, s1 - e0);
            int sidx = 0; float ns = 0.f;
            if (lane < cnt) { sidx = csr[e0 + lane]; ns = norm[sidx]; }
            for (int j = 0; j < cnt; ++j) {
                int sj = __shfl(sidx, j);
                float nj = __shfl(ns, j);
                accI = fmaf(nj, inI[(size_t)sj * 64 + lane], accI);
                accP = fmaf(nj, inP[(size_t)sj * 64 + lane], accP);
            }
        }
        float nn = norm[n];
        outI[(size_t)n * 64 + lane] = accI * nn;
        outP[(size_t)n * 64 + lane] = accP * nn;
    }
}

// ---------------- indicator build ----------------
__global__ void k_ind(const int* __restrict__ user, const int* __restrict__ itp,
                      const int* __restrict__ itn,
                      float* __restrict__ item_ind, float* __restrict__ user_ind,
                      int B, int NUSER) {
    int stride = gridDim.x * blockDim.x;
    for (int b = blockIdx.x * blockDim.x + threadIdx.x; b < B; b += stride) {
        item_ind[itp[b] + NUSER] = 1.f;
        item_ind[itn[b] + NUSER] = 1.f;
        user_ind[user[b]] = 1.f;
    }
}

// ---------------- batched losses: wave per batch row ----------------
__global__ void k_loss(const float* __restrict__ eI, const float* __restrict__ h1I, const float* __restrict__ h2I,
                       const float* __restrict__ eP, const float* __restrict__ h1P, const float* __restrict__ h2P,
                       const int* __restrict__ user, const int* __restrict__ itp, const int* __restrict__ itn,
                       const void* __restrict__ maskp, const int* __restrict__ flag,
                       float* __restrict__ acc, int B, int NUSER) {
    int lane = threadIdx.x & 63;
    int wib = threadIdx.x >> 6;
    int b = (blockIdx.x * blockDim.x + threadIdx.x) >> 6;
    __shared__ float part[4][3];
    float r0 = 0.f, r1 = 0.f, r2 = 0.f;
    if (b < B) {
        int u = user[b];
        int ip = itp[b] + NUSER;
        int in_ = itn[b] + NUSER;
        float uI = fval(eI, h1I, h2I, u, lane);
        float pI = fval(eI, h1I, h2I, ip, lane);
        float nI = fval(eI, h1I, h2I, in_, lane);
        float uP = fval(eP, h1P, h2P, u, lane);
        float pP = fval(eP, h1P, h2P, ip, lane);
        float nP = fval(eP, h1P, h2P, in_, lane);
        float dpI = uI * pI, dnI = uI * nI, dpP = uP * pP, dnP = uP * nP;
        for (int off = 32; off > 0; off >>= 1) {
            dpI += __shfl_xor(dpI, off);
            dnI += __shfl_xor(dnI, off);
            dpP += __shfl_xor(dpP, off);
            dnP += __shfl_xor(dnP, off);
        }
        if (lane == 0) {
            float m = (*flag) ? (float)(((const int*)maskp)[b] != 0)
                              : (float)(((const unsigned char*)maskp)[b] != 0);
            r0 = log_sigmoid(dpI + dpP - dnI - dnP);
            r1 = m * log_sigmoid(dpI - dnI);
            r2 = m * log_sigmoid(dnP - dpP) + (1.f - m) * log_sigmoid(dpP - dnP);
        }
    }
    if (lane == 0) { part[wib][0] = r0; part[wib][1] = r1; part[wib][2] = r2; }
    __syncthreads();
    if (threadIdx.x == 0) {
        float s0 = 0.f, s1 = 0.f, s2 = 0.f;
        for (int w = 0; w < 4; ++w) { s0 += part[w][0]; s1 += part[w][1]; s2 += part[w][2]; }
        atomicAdd(&acc[0], s0); atomicAdd(&acc[1], s1); atomicAdd(&acc[2], s2);
    }
}

// ---------------- discrepancy reduction: wave per node ----------------
__global__ void k_disc(const float* __restrict__ eI, const float* __restrict__ h1I, const float* __restrict__ h2I,
                       const float* __restrict__ eP, const float* __restrict__ h1P, const float* __restrict__ h2P,
                       const float* __restrict__ item_ind, const float* __restrict__ user_ind,
                       float* __restrict__ acc, int N) {
    int lane = threadIdx.x & 63;
    int wib = threadIdx.x >> 6;
    int wid = (blockIdx.x * blockDim.x + threadIdx.x) >> 6;
    int nw = (gridDim.x * blockDim.x) >> 6;
    float sI = 0.f, sU = 0.f, cI = 0.f, cU = 0.f;
    for (int n = wid; n < N; n += nw) {
        float d = fval(eI, h1I, h2I, n, lane) - fval(eP, h1P, h2P, n, lane);
        float d2 = d * d;
        float ii = item_ind[n], ui = user_ind[n];
        sI += ii * d2; sU += ui * d2;
        if (lane == 0) { cI += ii; cU += ui; }
    }
    for (int off = 32; off > 0; off >>= 1) { sI += __shfl_xor(sI, off); sU += __shfl_xor(sU, off); }
    __shared__ float part[4][4];
    if (lane == 0) { part[wib][0] = sI; part[wib][1] = cI; part[wib][2] = sU; part[wib][3] = cU; }
    __syncthreads();
    if (threadIdx.x == 0) {
        float a = 0.f, b = 0.f, c = 0.f, d = 0.f;
        for (int w = 0; w < 4; ++w) { a += part[w][0]; b += part[w][1]; c += part[w][2]; d += part[w][3]; }
        atomicAdd(&acc[3], a); atomicAdd(&acc[4], b); atomicAdd(&acc[5], c); atomicAdd(&acc[6], d);
    }
}

__global__ void k_final(const float* __restrict__ acc, float* __restrict__ out, int B) {
    if (threadIdx.x == 0 && blockIdx.x == 0) {
        float invB = 1.f / (float)B;
        out[0] = -acc[0] * invB;
        out[1] = -0.1f * acc[1] * invB;
        out[2] = -0.1f * acc[2] * invB;
        float disc = acc[3] / (fmaxf(acc[4], 1.f) * 64.f) + acc[5] / (fmaxf(acc[6], 1.f) * 64.f);
        out[3] = -0.01f * disc;
    }
}

extern "C" void kernel_launch(void* const* d_in, const int* in_sizes, int n_in,
                              void* d_out, int out_size, void* d_ws, size_t ws_size,
                              hipStream_t stream) {
    const float* emb_int = (const float*)d_in[0];
    const float* emb_pop = (const float*)d_in[1];
    const int* user   = (const int*)d_in[2];
    const int* item_p = (const int*)d_in[3];
    const int* item_n = (const int*)d_in[4];
    const void* mask  = d_in[5];
    const int* src    = (const int*)d_in[6];
    const int* dst    = (const int*)d_in[7];

    const int D = 64;
    const int N = in_sizes[0] / D;   // 150000
    const int B = in_sizes[2];       // 4096
    const int E = in_sizes[6];       // 4000000
    const int NUSER = 100000;
    const int nb = (N + KNODES - 1) >> KSHIFT;   // 293

    char* ws = (char*)d_ws;
    size_t off = 0;
    auto take = [&](size_t bytes) -> void* {
        void* p = ws + off;
        off += (bytes + 255) & ~(size_t)255;
        return p;
    };
    float* acc      = (float*)take(256);            // acc[0..6]; flag at acc[15]
    float* item_ind = (float*)take((size_t)N * 4);
    float* user_ind = (float*)take((size_t)N * 4);
    u32*   bcnt     = (u32*)take((size_t)nb * 4);
    size_t zero_bytes = off;                         // region zeroed each call
    u32*   bstart   = (u32*)take((size_t)(nb + 1) * 4);
    u32*   bfill    = (u32*)take((size_t)nb * 4);
    u32*   rowstart = (u32*)take((size_t)(N + 1) * 4);
    float* norm     = (float*)take((size_t)N * 4);
    int*   csr      = (int*)take((size_t)E * 4);
    float* h1I      = (float*)take((size_t)N * D * 4);
    float* h1P      = (float*)take((size_t)N * D * 4);
    float* h2I      = (float*)take((size_t)N * D * 4);
    float* h2P      = (float*)take((size_t)N * D * 4);
    u32*   packed   = (u32*)h2P;      // alias: packed dead before h2P is written
    int* flag = (int*)acc + 15;

    hipMemsetAsync(d_ws, 0, zero_bytes, stream);

    k_bhist<<<512, 256, 0, stream>>>(dst, bcnt, E, nb);
    k_bscan<<<1, 64, 0, stream>>>(bcnt, bstart, bfill, nb, (u32)E, rowstart, N);
    k_bscatter<<<(E + CHUNK - 1) / CHUNK, 256, 0, stream>>>(src, dst, bfill, packed, E, nb);
    k_bbuild<<<nb, 256, 0, stream>>>(packed, bstart, rowstart, norm, csr, N);
    k_mask_detect<<<1, 256, 0, stream>>>((const int*)mask, flag);

    // layer 1: h1 = norm .* (A (norm .* emb))
    k_pull<<<2048, 256, 0, stream>>>(emb_int, emb_pop, h1I, h1P, csr, rowstart, norm, N);
    // layer 2: h2 = norm .* (A (norm .* h1))
    k_pull<<<2048, 256, 0, stream>>>(h1I, h1P, h2I, h2P, csr, rowstart, norm, N);

    k_ind<<<64, 256, 0, stream>>>(user, item_p, item_n, item_ind, user_ind, B, NUSER);
    k_loss<<<(B * 64 + 255) / 256, 256, 0, stream>>>(emb_int, h1I, h2I, emb_pop, h1P, h2P,
                                                     user, item_p, item_n, mask, flag, acc, B, NUSER);
    k_disc<<<512, 256, 0, stream>>>(emb_int, h1I, h2I, emb_pop, h1P, h2P,
                                    item_ind, user_ind, acc, N);
    k_final<<<1, 64, 0, stream>>>(acc, (float*)d_out, B);
}

// Round 3
// 540.320 us; speedup vs baseline: 2.3065x; 1.6125x over previous
//
#include <hip/hip_runtime.h>
#include <hip/hip_bf16.h>

typedef unsigned int u32;

#define KNODES 512
#define KSHIFT 9
#define NBMAX 1024
#define CHUNK 4096

__device__ __forceinline__ float log_sigmoid(float x) {
    return fminf(x, 0.f) - log1pf(expf(-fabsf(x)));
}

// bf16-pair helpers: uint = (hi bf16 = odd dim) << 16 | (lo bf16 = even dim)
__device__ __forceinline__ float bl(u32 u) { return __uint_as_float(u << 16); }
__device__ __forceinline__ float bh(u32 u) { return __uint_as_float(u & 0xFFFF0000u); }
__device__ __forceinline__ u32 pack_bf16(float a, float b) {
    u32 ua = __float_as_uint(a), ub = __float_as_uint(b);
    u32 ra = (ua + 0x7FFFu + ((ua >> 16) & 1u)) >> 16;
    u32 rb = (ub + 0x7FFFu + ((ub >> 16) & 1u)) >> 16;
    return (rb << 16) | ra;
}

// ---------------- bucket histogram (buckets of 512 nodes) ----------------
__global__ void k_bhist(const int* __restrict__ dst, u32* __restrict__ bcnt, int E, int nb) {
    __shared__ u32 h[NBMAX];
    for (int i = threadIdx.x; i < nb; i += blockDim.x) h[i] = 0;
    __syncthreads();
    int stride = gridDim.x * blockDim.x;
    for (int e = blockIdx.x * blockDim.x + threadIdx.x; e < E; e += stride)
        atomicAdd(&h[((u32)dst[e]) >> KSHIFT], 1u);
    __syncthreads();
    for (int i = threadIdx.x; i < nb; i += blockDim.x)
        if (h[i]) atomicAdd(&bcnt[i], h[i]);
}

// ---------------- bucket scan (tiny) ----------------
__global__ void k_bscan(const u32* __restrict__ bcnt, u32* __restrict__ bstart,
                        u32* __restrict__ bfill, int nb, u32 E,
                        u32* __restrict__ rowstart, int N) {
    if (threadIdx.x == 0 && blockIdx.x == 0) {
        u32 run = 0;
        for (int i = 0; i < nb; ++i) { bstart[i] = run; bfill[i] = run; run += bcnt[i]; }
        bstart[nb] = run;
        rowstart[N] = E;
    }
}

// ---------------- scatter edges into bucket-contiguous packed array ----------------
// pack = (local_dst[9b] << 18) | src[18b]
__global__ void k_bscatter(const int* __restrict__ src, const int* __restrict__ dst,
                           u32* __restrict__ bfill, u32* __restrict__ packed, int E, int nb) {
    __shared__ u32 h[NBMAX];
    const int t = threadIdx.x;
    const int base = blockIdx.x * CHUNK;
    const int PT = CHUNK / 256; // 16
    u32 dv[PT], sv[PT];
#pragma unroll
    for (int i = 0; i < PT; ++i) {
        int e = base + t + i * 256;
        if (e < E) { dv[i] = (u32)dst[e]; sv[i] = (u32)src[e]; }
        else dv[i] = 0xFFFFFFFFu;
    }
    for (int i = t; i < nb; i += 256) h[i] = 0;
    __syncthreads();
#pragma unroll
    for (int i = 0; i < PT; ++i)
        if (dv[i] != 0xFFFFFFFFu) atomicAdd(&h[dv[i] >> KSHIFT], 1u);
    __syncthreads();
    for (int i = t; i < nb; i += 256) {
        u32 c = h[i];
        h[i] = c ? atomicAdd(&bfill[i], c) : 0u;
    }
    __syncthreads();
#pragma unroll
    for (int i = 0; i < PT; ++i) {
        if (dv[i] != 0xFFFFFFFFu) {
            u32 b = dv[i] >> KSHIFT;
            u32 pos = atomicAdd(&h[b], 1u);
            packed[pos] = ((dv[i] & (KNODES - 1)) << 18) | sv[i];
        }
    }
}

// ---------------- per-bucket CSR build: deg, rowstart, norms, csr ----------------
__global__ void k_bbuild(const u32* __restrict__ packed, const u32* __restrict__ bstart,
                         u32* __restrict__ rowstart, float* __restrict__ norm,
                         float* __restrict__ norm2, float* __restrict__ snorm,
                         int* __restrict__ csr, int N) {
    __shared__ u32 deg[KNODES], fill[KNODES], s256[256];
    const int t = threadIdx.x;
    const int bkt = blockIdx.x;
    const int nodeBase = bkt << KSHIFT;
    u32 e0 = bstart[bkt], e1 = bstart[bkt + 1];
    deg[t] = 0; deg[t + 256] = 0;
    __syncthreads();
    for (u32 e = e0 + t; e < e1; e += 256)
        atomicAdd(&deg[packed[e] >> 18], 1u);
    __syncthreads();
    u32 a = deg[2 * t], b = deg[2 * t + 1];
    s256[t] = a + b;
    __syncthreads();
    for (int off = 1; off < 256; off <<= 1) {
        u32 x = (t >= off) ? s256[t - off] : 0u;
        __syncthreads();
        s256[t] += x;
        __syncthreads();
    }
    u32 ebase = (t ? s256[t - 1] : 0u);
    fill[2 * t] = ebase;
    fill[2 * t + 1] = ebase + a;
    int n0 = nodeBase + 2 * t, n1 = nodeBase + 2 * t + 1;
    if (n0 < N) {
        float da = fmaxf((float)a, 1.f);
        float nr = rsqrtf(da);
        rowstart[n0] = e0 + ebase; norm[n0] = nr; norm2[n0] = nr * nr; snorm[n0] = sqrtf(da);
    }
    if (n1 < N) {
        float db = fmaxf((float)b, 1.f);
        float nr = rsqrtf(db);
        rowstart[n1] = e0 + ebase + a; norm[n1] = nr; norm2[n1] = nr * nr; snorm[n1] = sqrtf(db);
    }
    __syncthreads();
    for (u32 e = e0 + t; e < e1; e += 256) {
        u32 p = packed[e];
        u32 ln = p >> 18;
        u32 pos = atomicAdd(&fill[ln], 1u);
        csr[e0 + pos] = (int)(p & 0x3FFFFu);
    }
}

// ---------------- pack: T0[n] = bf16(norm[n] * emb), I in lanes 0-31, P in 32-63 ----------------
__global__ void k_pack(const float* __restrict__ eI, const float* __restrict__ eP,
                       const float* __restrict__ norm, u32* __restrict__ T0, int N) {
    int idx = blockIdx.x * blockDim.x + threadIdx.x;
    int total = N * 64;
    int stride = gridDim.x * blockDim.x;
    for (; idx < total; idx += stride) {
        int n = idx >> 6, l = idx & 63;
        int half = l >> 5, lh = l & 31;
        const float* e = half ? eP : eI;
        float2 v = *(const float2*)&e[(size_t)n * 64 + 2 * lh];
        float nr = norm[n];
        T0[idx] = pack_bf16(v.x * nr, v.y * nr);
    }
}

// ---------------- mask dtype detection (bool-as-uint8 vs int32) ----------------
__global__ void k_mask_detect(const int* __restrict__ m, int* flag) {
    __shared__ int allok;
    if (threadIdx.x == 0) allok = 1;
    __syncthreads();
    bool ok = true;
    for (int i = threadIdx.x; i < 1024; i += blockDim.x) {
        int v = m[i];
        if (v != 0 && v != 1) ok = false;
    }
    if (!ok) allok = 0;
    __syncthreads();
    if (threadIdx.x == 0) flag[0] = allok;   // 1 => int32 mask, 0 => byte mask
}

// ---------------- propagation: wave per node, pure bf16 row-sum ----------------
// Tout[n] = norm2[n] * sum_{s in row(n)} Tin[s]
__global__ void k_pull(const u32* __restrict__ Tin, u32* __restrict__ Tout,
                       const int* __restrict__ csr, const u32* __restrict__ rowstart,
                       const float* __restrict__ norm2, int N) {
    int lane = threadIdx.x & 63;
    int wid = (blockIdx.x * blockDim.x + threadIdx.x) >> 6;
    int nw = (gridDim.x * blockDim.x) >> 6;
    for (int n = wid; n < N; n += nw) {
        u32 s0 = rowstart[n], s1 = rowstart[n + 1];
        float a0 = 0.f, a1 = 0.f;
        for (u32 e0 = s0; e0 < s1; e0 += 64) {
            int cnt = (int)min(64u, s1 - e0);
            int sidx = (lane < cnt) ? csr[e0 + lane] : 0;
            int j = 0;
            for (; j + 4 <= cnt; j += 4) {
                int sa = __shfl(sidx, j), sb = __shfl(sidx, j + 1);
                int sc = __shfl(sidx, j + 2), sd = __shfl(sidx, j + 3);
                u32 ua = Tin[(size_t)sa * 64 + lane];
                u32 ub = Tin[(size_t)sb * 64 + lane];
                u32 uc = Tin[(size_t)sc * 64 + lane];
                u32 ud = Tin[(size_t)sd * 64 + lane];
                a0 += bl(ua); a1 += bh(ua);
                a0 += bl(ub); a1 += bh(ub);
                a0 += bl(uc); a1 += bh(uc);
                a0 += bl(ud); a1 += bh(ud);
            }
            for (; j < cnt; ++j) {
                int sj = __shfl(sidx, j);
                u32 u = Tin[(size_t)sj * 64 + lane];
                a0 += bl(u); a1 += bh(u);
            }
        }
        float nn = norm2[n];
        Tout[(size_t)n * 64 + lane] = pack_bf16(a0 * nn, a1 * nn);
    }
}

// ---------------- indicator build ----------------
__global__ void k_ind(const int* __restrict__ user, const int* __restrict__ itp,
                      const int* __restrict__ itn,
                      float* __restrict__ item_ind, float* __restrict__ user_ind,
                      int B, int NUSER) {
    int stride = gridDim.x * blockDim.x;
    for (int b = blockIdx.x * blockDim.x + threadIdx.x; b < B; b += stride) {
        item_ind[itp[b] + NUSER] = 1.f;
        item_ind[itn[b] + NUSER] = 1.f;
        user_ind[user[b]] = 1.f;
    }
}

// f dims (2lh, 2lh+1) of table (lane<32 ? int : pop) for row r
__device__ __forceinline__ void fval2(const float* __restrict__ eb,
                                      const u32* __restrict__ T1, const u32* __restrict__ T2,
                                      const float* __restrict__ snorm,
                                      int r, int lane, int lh, float& f0, float& f1) {
    float2 ev = *(const float2*)&eb[(size_t)r * 64 + 2 * lh];
    u32 t1 = T1[(size_t)r * 64 + lane];
    u32 t2 = T2[(size_t)r * 64 + lane];
    float sr = snorm[r];
    f0 = (ev.x + sr * (bl(t1) + bl(t2))) * (1.f / 3.f);
    f1 = (ev.y + sr * (bh(t1) + bh(t2))) * (1.f / 3.f);
}

// ---------------- batched losses: wave per batch row ----------------
__global__ void k_loss(const float* __restrict__ eI, const float* __restrict__ eP,
                       const u32* __restrict__ T1, const u32* __restrict__ T2,
                       const float* __restrict__ snorm,
                       const int* __restrict__ user, const int* __restrict__ itp, const int* __restrict__ itn,
                       const void* __restrict__ maskp, const int* __restrict__ flag,
                       float* __restrict__ acc, int B, int NUSER) {
    int lane = threadIdx.x & 63;
    int wib = threadIdx.x >> 6;
    int b = (blockIdx.x * blockDim.x + threadIdx.x) >> 6;
    __shared__ float part[4][3];
    float r0 = 0.f, r1 = 0.f, r2 = 0.f;
    if (b < B) {
        int u = user[b];
        int ip = itp[b] + NUSER;
        int in_ = itn[b] + NUSER;
        int half = lane >> 5, lh = lane & 31;
        const float* eb = half ? eP : eI;
        float u0, u1, p0, p1, n0, n1;
        fval2(eb, T1, T2, snorm, u,   lane, lh, u0, u1);
        fval2(eb, T1, T2, snorm, ip,  lane, lh, p0, p1);
        fval2(eb, T1, T2, snorm, in_, lane, lh, n0, n1);
        float dp = u0 * p0 + u1 * p1;
        float dn = u0 * n0 + u1 * n1;
        for (int off = 1; off < 32; off <<= 1) {
            dp += __shfl_xor(dp, off);
            dn += __shfl_xor(dn, off);
        }
        float dpI = __shfl(dp, 0), dpP = __shfl(dp, 32);
        float dnI = __shfl(dn, 0), dnP = __shfl(dn, 32);
        if (lane == 0) {
            float m = (*flag) ? (float)(((const int*)maskp)[b] != 0)
                              : (float)(((const unsigned char*)maskp)[b] != 0);
            r0 = log_sigmoid(dpI + dpP - dnI - dnP);
            r1 = m * log_sigmoid(dpI - dnI);
            r2 = m * log_sigmoid(dnP - dpP) + (1.f - m) * log_sigmoid(dpP - dnP);
        }
    }
    if (lane == 0) { part[wib][0] = r0; part[wib][1] = r1; part[wib][2] = r2; }
    __syncthreads();
    if (threadIdx.x == 0) {
        float s0 = 0.f, s1 = 0.f, s2 = 0.f;
        for (int w = 0; w < 4; ++w) { s0 += part[w][0]; s1 += part[w][1]; s2 += part[w][2]; }
        atomicAdd(&acc[0], s0); atomicAdd(&acc[1], s1); atomicAdd(&acc[2], s2);
    }
}

// ---------------- discrepancy: wave per node ----------------
__global__ void k_disc(const float* __restrict__ eI, const float* __restrict__ eP,
                       const u32* __restrict__ T1, const u32* __restrict__ T2,
                       const float* __restrict__ snorm,
                       const float* __restrict__ item_ind, const float* __restrict__ user_ind,
                       float* __restrict__ acc, int N) {
    int lane = threadIdx.x & 63;
    int wib = threadIdx.x >> 6;
    int wid = (blockIdx.x * blockDim.x + threadIdx.x) >> 6;
    int nw = (gridDim.x * blockDim.x) >> 6;
    int half = lane >> 5, lh = lane & 31;
    const float* eb = half ? eP : eI;
    float sI = 0.f, sU = 0.f, cI = 0.f, cU = 0.f;
    for (int n = wid; n < N; n += nw) {
        float f0, f1;
        fval2(eb, T1, T2, snorm, n, lane, lh, f0, f1);
        float o0 = __shfl_xor(f0, 32), o1 = __shfl_xor(f1, 32);
        float d0 = f0 - o0, d1 = f1 - o1;
        float dd = d0 * d0 + d1 * d1;          // identical in both halves (double count)
        float ii = item_ind[n], ui = user_ind[n];
        sI += ii * dd; sU += ui * dd;
        if (lane == 0) { cI += ii; cU += ui; }
    }
    for (int off = 1; off < 64; off <<= 1) { sI += __shfl_xor(sI, off); sU += __shfl_xor(sU, off); }
    __shared__ float part[4][4];
    if (lane == 0) { part[wib][0] = 0.5f * sI; part[wib][1] = cI; part[wib][2] = 0.5f * sU; part[wib][3] = cU; }
    __syncthreads();
    if (threadIdx.x == 0) {
        float a = 0.f, b = 0.f, c = 0.f, d = 0.f;
        for (int w = 0; w < 4; ++w) { a += part[w][0]; b += part[w][1]; c += part[w][2]; d += part[w][3]; }
        atomicAdd(&acc[3], a); atomicAdd(&acc[4], b); atomicAdd(&acc[5], c); atomicAdd(&acc[6], d);
    }
}

__global__ void k_final(const float* __restrict__ acc, float* __restrict__ out, int B) {
    if (threadIdx.x == 0 && blockIdx.x == 0) {
        float invB = 1.f / (float)B;
        out[0] = -acc[0] * invB;
        out[1] = -0.1f * acc[1] * invB;
        out[2] = -0.1f * acc[2] * invB;
        float disc = acc[3] / (fmaxf(acc[4], 1.f) * 64.f) + acc[5] / (fmaxf(acc[6], 1.f) * 64.f);
        out[3] = -0.01f * disc;
    }
}

extern "C" void kernel_launch(void* const* d_in, const int* in_sizes, int n_in,
                              void* d_out, int out_size, void* d_ws, size_t ws_size,
                              hipStream_t stream) {
    const float* emb_int = (const float*)d_in[0];
    const float* emb_pop = (const float*)d_in[1];
    const int* user   = (const int*)d_in[2];
    const int* item_p = (const int*)d_in[3];
    const int* item_n = (const int*)d_in[4];
    const void* mask  = d_in[5];
    const int* src    = (const int*)d_in[6];
    const int* dst    = (const int*)d_in[7];

    const int D = 64;
    const int N = in_sizes[0] / D;   // 150000
    const int B = in_sizes[2];       // 4096
    const int E = in_sizes[6];       // 4000000
    const int NUSER = 100000;
    const int nb = (N + KNODES - 1) >> KSHIFT;   // 293

    char* ws = (char*)d_ws;
    size_t off = 0;
    auto take = [&](size_t bytes) -> void* {
        void* p = ws + off;
        off += (bytes + 255) & ~(size_t)255;
        return p;
    };
    float* acc      = (float*)take(256);            // acc[0..6]; flag at acc[15]
    float* item_ind = (float*)take((size_t)N * 4);
    float* user_ind = (float*)take((size_t)N * 4);
    u32*   bcnt     = (u32*)take((size_t)nb * 4);
    size_t zero_bytes = off;                         // region zeroed each call
    u32*   bstart   = (u32*)take((size_t)(nb + 1) * 4);
    u32*   bfill    = (u32*)take((size_t)nb * 4);
    u32*   rowstart = (u32*)take((size_t)(N + 1) * 4);
    float* norm     = (float*)take((size_t)N * 4);
    float* norm2    = (float*)take((size_t)N * 4);
    float* snorm    = (float*)take((size_t)N * 4);
    int*   csr      = (int*)take((size_t)E * 4);
    u32*   T0       = (u32*)take((size_t)N * D * 4);
    u32*   T1       = (u32*)take((size_t)N * D * 4);
    u32*   T2       = (u32*)take((size_t)N * D * 4);
    u32*   packed   = (u32*)T2;      // alias: packed dead before T2 is written
    int* flag = (int*)acc + 15;

    hipMemsetAsync(d_ws, 0, zero_bytes, stream);

    k_bhist<<<512, 256, 0, stream>>>(dst, bcnt, E, nb);
    k_bscan<<<1, 64, 0, stream>>>(bcnt, bstart, bfill, nb, (u32)E, rowstart, N);
    k_bscatter<<<(E + CHUNK - 1) / CHUNK, 256, 0, stream>>>(src, dst, bfill, packed, E, nb);
    k_bbuild<<<nb, 256, 0, stream>>>(packed, bstart, rowstart, norm, norm2, snorm, csr, N);
    k_pack<<<2048, 256, 0, stream>>>(emb_int, emb_pop, norm, T0, N);
    k_mask_detect<<<1, 256, 0, stream>>>((const int*)mask, flag);

    // layer 1: T1 = norm^2 .* (A T0)
    k_pull<<<2048, 256, 0, stream>>>(T0, T1, csr, rowstart, norm2, N);
    // layer 2: T2 = norm^2 .* (A T1)
    k_pull<<<2048, 256, 0, stream>>>(T1, T2, csr, rowstart, norm2, N);

    k_ind<<<64, 256, 0, stream>>>(user, item_p, item_n, item_ind, user_ind, B, NUSER);
    k_loss<<<(B * 64 + 255) / 256, 256, 0, stream>>>(emb_int, emb_pop, T1, T2, snorm,
                                                     user, item_p, item_n, mask, flag, acc, B, NUSER);
    k_disc<<<512, 256, 0, stream>>>(emb_int, emb_pop, T1, T2, snorm,
                                    item_ind, user_ind, acc, N);
    k_final<<<1, 64, 0, stream>>>(acc, (float*)d_out, B);
}

// Round 4
// 521.398 us; speedup vs baseline: 2.3902x; 1.0363x over previous
//
#include <hip/hip_runtime.h>
#include <hip/hip_bf16.h>

typedef unsigned int u32;

#define KNODES 512
#define KSHIFT 9
#define NBMAX 1024
#define CHUNK 4096

__device__ __forceinline__ float log_sigmoid(float x) {
    return fminf(x, 0.f) - log1pf(expf(-fabsf(x)));
}

// bf16-pair helpers: uint = (hi bf16 = odd dim) << 16 | (lo bf16 = even dim)
__device__ __forceinline__ float bl(u32 u) { return __uint_as_float(u << 16); }
__device__ __forceinline__ float bh(u32 u) { return __uint_as_float(u & 0xFFFF0000u); }
__device__ __forceinline__ u32 pack_bf16(float a, float b) {
    u32 ua = __float_as_uint(a), ub = __float_as_uint(b);
    u32 ra = (ua + 0x7FFFu + ((ua >> 16) & 1u)) >> 16;
    u32 rb = (ub + 0x7FFFu + ((ub >> 16) & 1u)) >> 16;
    return (rb << 16) | ra;
}

// ---------------- bucket histogram (buckets of 512 nodes) ----------------
__global__ void k_bhist(const int* __restrict__ dst, u32* __restrict__ bcnt, int E, int nb) {
    __shared__ u32 h[NBMAX];
    for (int i = threadIdx.x; i < nb; i += blockDim.x) h[i] = 0;
    __syncthreads();
    int stride = gridDim.x * blockDim.x;
    for (int e = blockIdx.x * blockDim.x + threadIdx.x; e < E; e += stride)
        atomicAdd(&h[((u32)dst[e]) >> KSHIFT], 1u);
    __syncthreads();
    for (int i = threadIdx.x; i < nb; i += blockDim.x)
        if (h[i]) atomicAdd(&bcnt[i], h[i]);
}

// ---------------- bucket scan (parallel, one block) ----------------
__global__ void k_bscan(const u32* __restrict__ bcnt, u32* __restrict__ bstart,
                        u32* __restrict__ bfill, int nb, u32 E,
                        u32* __restrict__ rowstart, int N) {
    __shared__ u32 lds[512];
    int t = threadIdx.x;
    u32 v = (t < nb) ? bcnt[t] : 0u;
    lds[t] = v;
    __syncthreads();
    for (int off = 1; off < 512; off <<= 1) {
        u32 x = (t >= off) ? lds[t - off] : 0u;
        __syncthreads();
        lds[t] += x;
        __syncthreads();
    }
    u32 incl = lds[t];
    u32 excl = incl - v;
    if (t < nb) { bstart[t] = excl; bfill[t] = excl; }
    if (t == nb - 1) bstart[nb] = incl;
    if (t == 0) rowstart[N] = E;
}

// ---------------- scatter edges into bucket-contiguous packed array ----------------
// pack = (local_dst[9b] << 18) | src[18b]
__global__ void k_bscatter(const int* __restrict__ src, const int* __restrict__ dst,
                           u32* __restrict__ bfill, u32* __restrict__ packed, int E, int nb) {
    __shared__ u32 h[NBMAX];
    const int t = threadIdx.x;
    const int base = blockIdx.x * CHUNK;
    const int PT = CHUNK / 256; // 16
    u32 dv[PT], sv[PT];
#pragma unroll
    for (int i = 0; i < PT; ++i) {
        int e = base + t + i * 256;
        if (e < E) { dv[i] = (u32)dst[e]; sv[i] = (u32)src[e]; }
        else dv[i] = 0xFFFFFFFFu;
    }
    for (int i = t; i < nb; i += 256) h[i] = 0;
    __syncthreads();
#pragma unroll
    for (int i = 0; i < PT; ++i)
        if (dv[i] != 0xFFFFFFFFu) atomicAdd(&h[dv[i] >> KSHIFT], 1u);
    __syncthreads();
    for (int i = t; i < nb; i += 256) {
        u32 c = h[i];
        h[i] = c ? atomicAdd(&bfill[i], c) : 0u;
    }
    __syncthreads();
#pragma unroll
    for (int i = 0; i < PT; ++i) {
        if (dv[i] != 0xFFFFFFFFu) {
            u32 b = dv[i] >> KSHIFT;
            u32 pos = atomicAdd(&h[b], 1u);
            packed[pos] = ((dv[i] & (KNODES - 1)) << 18) | sv[i];
        }
    }
}

// ---------------- per-bucket CSR build: deg, rowstart, norms, csr ----------------
__global__ void k_bbuild(const u32* __restrict__ packed, const u32* __restrict__ bstart,
                         u32* __restrict__ rowstart, float* __restrict__ norm,
                         float* __restrict__ norm2, float* __restrict__ snorm,
                         int* __restrict__ csr, int N) {
    __shared__ u32 deg[KNODES], fill[KNODES], s256[256];
    const int t = threadIdx.x;
    const int bkt = blockIdx.x;
    const int nodeBase = bkt << KSHIFT;
    u32 e0 = bstart[bkt], e1 = bstart[bkt + 1];
    deg[t] = 0; deg[t + 256] = 0;
    __syncthreads();
    for (u32 e = e0 + t; e < e1; e += 256)
        atomicAdd(&deg[packed[e] >> 18], 1u);
    __syncthreads();
    u32 a = deg[2 * t], b = deg[2 * t + 1];
    s256[t] = a + b;
    __syncthreads();
    for (int off = 1; off < 256; off <<= 1) {
        u32 x = (t >= off) ? s256[t - off] : 0u;
        __syncthreads();
        s256[t] += x;
        __syncthreads();
    }
    u32 ebase = (t ? s256[t - 1] : 0u);
    fill[2 * t] = ebase;
    fill[2 * t + 1] = ebase + a;
    int n0 = nodeBase + 2 * t, n1 = nodeBase + 2 * t + 1;
    if (n0 < N) {
        float da = fmaxf((float)a, 1.f);
        float nr = rsqrtf(da);
        rowstart[n0] = e0 + ebase; norm[n0] = nr; norm2[n0] = nr * nr; snorm[n0] = sqrtf(da);
    }
    if (n1 < N) {
        float db = fmaxf((float)b, 1.f);
        float nr = rsqrtf(db);
        rowstart[n1] = e0 + ebase + a; norm[n1] = nr; norm2[n1] = nr * nr; snorm[n1] = sqrtf(db);
    }
    __syncthreads();
    for (u32 e = e0 + t; e < e1; e += 256) {
        u32 p = packed[e];
        u32 ln = p >> 18;
        u32 pos = atomicAdd(&fill[ln], 1u);
        csr[e0 + pos] = (int)(p & 0x3FFFFu);
    }
}

// ---------------- pack: T0[n] = bf16(norm[n] * emb), I in lanes 0-31, P in 32-63 ----------------
__global__ void k_pack(const float* __restrict__ eI, const float* __restrict__ eP,
                       const float* __restrict__ norm, u32* __restrict__ T0, int N) {
    int idx = blockIdx.x * blockDim.x + threadIdx.x;
    int total = N * 64;
    int stride = gridDim.x * blockDim.x;
    for (; idx < total; idx += stride) {
        int n = idx >> 6, l = idx & 63;
        int half = l >> 5, lh = l & 31;
        const float* e = half ? eP : eI;
        float2 v = *(const float2*)&e[(size_t)n * 64 + 2 * lh];
        float nr = norm[n];
        T0[idx] = pack_bf16(v.x * nr, v.y * nr);
    }
}

// ---------------- mask dtype detection (bool-as-uint8 vs int32) ----------------
__global__ void k_mask_detect(const int* __restrict__ m, int* flag) {
    __shared__ int allok;
    if (threadIdx.x == 0) allok = 1;
    __syncthreads();
    bool ok = true;
    for (int i = threadIdx.x; i < 1024; i += blockDim.x) {
        int v = m[i];
        if (v != 0 && v != 1) ok = false;
    }
    if (!ok) allok = 0;
    __syncthreads();
    if (threadIdx.x == 0) flag[0] = allok;   // 1 => int32 mask, 0 => byte mask
}

// ---------------- propagation: wave per node, 4 edges/iter via uint4 ----------------
// lane = grp*16 + r: grp picks edge within quad, r picks 16B chunk of the 256B row.
// Tout[n] = norm2[n] * sum_{s in row(n)} Tin[s]
__global__ void k_pull(const u32* __restrict__ Tin, u32* __restrict__ Tout,
                       const int* __restrict__ csr, const u32* __restrict__ rowstart,
                       const float* __restrict__ norm2, int N) {
    int lane = threadIdx.x & 63;
    int grp = lane >> 4;     // 0..3
    int r = lane & 15;       // 0..15
    int wid = (blockIdx.x * blockDim.x + threadIdx.x) >> 6;
    int nw = (gridDim.x * blockDim.x) >> 6;
    for (int n = wid; n < N; n += nw) {
        u32 s0 = rowstart[n], s1 = rowstart[n + 1];
        float a0 = 0.f, a1 = 0.f, a2 = 0.f, a3 = 0.f, a4 = 0.f, a5 = 0.f, a6 = 0.f, a7 = 0.f;
        for (u32 e0 = s0; e0 < s1; e0 += 64) {
            int cnt = (int)min(64u, s1 - e0);
            int sidx = (lane < cnt) ? csr[e0 + lane] : 0;
            int j = 0;
            for (; j + 8 <= cnt; j += 8) {
                int sA = __shfl(sidx, j + grp);
                int sB = __shfl(sidx, j + 4 + grp);
                uint4 uA = *(const uint4*)&Tin[(size_t)sA * 64 + 4 * r];
                uint4 uB = *(const uint4*)&Tin[(size_t)sB * 64 + 4 * r];
                a0 += bl(uA.x); a1 += bh(uA.x); a2 += bl(uA.y); a3 += bh(uA.y);
                a4 += bl(uA.z); a5 += bh(uA.z); a6 += bl(uA.w); a7 += bh(uA.w);
                a0 += bl(uB.x); a1 += bh(uB.x); a2 += bl(uB.y); a3 += bh(uB.y);
                a4 += bl(uB.z); a5 += bh(uB.z); a6 += bl(uB.w); a7 += bh(uB.w);
            }
            for (; j + 4 <= cnt; j += 4) {
                int sA = __shfl(sidx, j + grp);
                uint4 uA = *(const uint4*)&Tin[(size_t)sA * 64 + 4 * r];
                a0 += bl(uA.x); a1 += bh(uA.x); a2 += bl(uA.y); a3 += bh(uA.y);
                a4 += bl(uA.z); a5 += bh(uA.z); a6 += bl(uA.w); a7 += bh(uA.w);
            }
            int rem = cnt - j;
            if (rem) {
                int jj = j + grp;
                int s = __shfl(sidx, (jj < cnt) ? jj : 0);
                if (grp < rem) {
                    uint4 u = *(const uint4*)&Tin[(size_t)s * 64 + 4 * r];
                    a0 += bl(u.x); a1 += bh(u.x); a2 += bl(u.y); a3 += bh(u.y);
                    a4 += bl(u.z); a5 += bh(u.z); a6 += bl(u.w); a7 += bh(u.w);
                }
            }
        }
        // merge the 4 edge-groups (lanes with equal r hold the same dims)
        a0 += __shfl_xor(a0, 16); a1 += __shfl_xor(a1, 16);
        a2 += __shfl_xor(a2, 16); a3 += __shfl_xor(a3, 16);
        a4 += __shfl_xor(a4, 16); a5 += __shfl_xor(a5, 16);
        a6 += __shfl_xor(a6, 16); a7 += __shfl_xor(a7, 16);
        a0 += __shfl_xor(a0, 32); a1 += __shfl_xor(a1, 32);
        a2 += __shfl_xor(a2, 32); a3 += __shfl_xor(a3, 32);
        a4 += __shfl_xor(a4, 32); a5 += __shfl_xor(a5, 32);
        a6 += __shfl_xor(a6, 32); a7 += __shfl_xor(a7, 32);
        float nn = norm2[n];
        if (lane < 16) {
            uint4 w;
            w.x = pack_bf16(a0 * nn, a1 * nn);
            w.y = pack_bf16(a2 * nn, a3 * nn);
            w.z = pack_bf16(a4 * nn, a5 * nn);
            w.w = pack_bf16(a6 * nn, a7 * nn);
            *(uint4*)&Tout[(size_t)n * 64 + 4 * r] = w;
        }
    }
}

// ---------------- indicator build ----------------
__global__ void k_ind(const int* __restrict__ user, const int* __restrict__ itp,
                      const int* __restrict__ itn,
                      float* __restrict__ item_ind, float* __restrict__ user_ind,
                      int B, int NUSER) {
    int stride = gridDim.x * blockDim.x;
    for (int b = blockIdx.x * blockDim.x + threadIdx.x; b < B; b += stride) {
        item_ind[itp[b] + NUSER] = 1.f;
        item_ind[itn[b] + NUSER] = 1.f;
        user_ind[user[b]] = 1.f;
    }
}

// f dims (2lh, 2lh+1) of table (lane<32 ? int : pop) for row r
__device__ __forceinline__ void fval2(const float* __restrict__ eb,
                                      const u32* __restrict__ T1, const u32* __restrict__ T2,
                                      const float* __restrict__ snorm,
                                      int r, int lane, int lh, float& f0, float& f1) {
    float2 ev = *(const float2*)&eb[(size_t)r * 64 + 2 * lh];
    u32 t1 = T1[(size_t)r * 64 + lane];
    u32 t2 = T2[(size_t)r * 64 + lane];
    float sr = snorm[r];
    f0 = (ev.x + sr * (bl(t1) + bl(t2))) * (1.f / 3.f);
    f1 = (ev.y + sr * (bh(t1) + bh(t2))) * (1.f / 3.f);
}

// ---------------- batched losses: wave per batch row ----------------
__global__ void k_loss(const float* __restrict__ eI, const float* __restrict__ eP,
                       const u32* __restrict__ T1, const u32* __restrict__ T2,
                       const float* __restrict__ snorm,
                       const int* __restrict__ user, const int* __restrict__ itp, const int* __restrict__ itn,
                       const void* __restrict__ maskp, const int* __restrict__ flag,
                       float* __restrict__ acc, int B, int NUSER) {
    int lane = threadIdx.x & 63;
    int wib = threadIdx.x >> 6;
    int b = (blockIdx.x * blockDim.x + threadIdx.x) >> 6;
    __shared__ float part[4][3];
    float r0 = 0.f, r1 = 0.f, r2 = 0.f;
    if (b < B) {
        int u = user[b];
        int ip = itp[b] + NUSER;
        int in_ = itn[b] + NUSER;
        int half = lane >> 5, lh = lane & 31;
        const float* eb = half ? eP : eI;
        float u0, u1, p0, p1, n0, n1;
        fval2(eb, T1, T2, snorm, u,   lane, lh, u0, u1);
        fval2(eb, T1, T2, snorm, ip,  lane, lh, p0, p1);
        fval2(eb, T1, T2, snorm, in_, lane, lh, n0, n1);
        float dp = u0 * p0 + u1 * p1;
        float dn = u0 * n0 + u1 * n1;
        for (int off = 1; off < 32; off <<= 1) {
            dp += __shfl_xor(dp, off);
            dn += __shfl_xor(dn, off);
        }
        float dpI = __shfl(dp, 0), dpP = __shfl(dp, 32);
        float dnI = __shfl(dn, 0), dnP = __shfl(dn, 32);
        if (lane == 0) {
            float m = (*flag) ? (float)(((const int*)maskp)[b] != 0)
                              : (float)(((const unsigned char*)maskp)[b] != 0);
            r0 = log_sigmoid(dpI + dpP - dnI - dnP);
            r1 = m * log_sigmoid(dpI - dnI);
            r2 = m * log_sigmoid(dnP - dpP) + (1.f - m) * log_sigmoid(dpP - dnP);
        }
    }
    if (lane == 0) { part[wib][0] = r0; part[wib][1] = r1; part[wib][2] = r2; }
    __syncthreads();
    if (threadIdx.x == 0) {
        float s0 = 0.f, s1 = 0.f, s2 = 0.f;
        for (int w = 0; w < 4; ++w) { s0 += part[w][0]; s1 += part[w][1]; s2 += part[w][2]; }
        atomicAdd(&acc[0], s0); atomicAdd(&acc[1], s1); atomicAdd(&acc[2], s2);
    }
}

// ---------------- discrepancy: wave per node ----------------
__global__ void k_disc(const float* __restrict__ eI, const float* __restrict__ eP,
                       const u32* __restrict__ T1, const u32* __restrict__ T2,
                       const float* __restrict__ snorm,
                       const float* __restrict__ item_ind, const float* __restrict__ user_ind,
                       float* __restrict__ acc, int N) {
    int lane = threadIdx.x & 63;
    int wib = threadIdx.x >> 6;
    int wid = (blockIdx.x * blockDim.x + threadIdx.x) >> 6;
    int nw = (gridDim.x * blockDim.x) >> 6;
    int half = lane >> 5, lh = lane & 31;
    const float* eb = half ? eP : eI;
    float sI = 0.f, sU = 0.f, cI = 0.f, cU = 0.f;
    for (int n = wid; n < N; n += nw) {
        float f0, f1;
        fval2(eb, T1, T2, snorm, n, lane, lh, f0, f1);
        float o0 = __shfl_xor(f0, 32), o1 = __shfl_xor(f1, 32);
        float d0 = f0 - o0, d1 = f1 - o1;
        float dd = d0 * d0 + d1 * d1;          // identical in both halves (double count)
        float ii = item_ind[n], ui = user_ind[n];
        sI += ii * dd; sU += ui * dd;
        if (lane == 0) { cI += ii; cU += ui; }
    }
    for (int off = 1; off < 64; off <<= 1) { sI += __shfl_xor(sI, off); sU += __shfl_xor(sU, off); }
    __shared__ float part[4][4];
    if (lane == 0) { part[wib][0] = 0.5f * sI; part[wib][1] = cI; part[wib][2] = 0.5f * sU; part[wib][3] = cU; }
    __syncthreads();
    if (threadIdx.x == 0) {
        float a = 0.f, b = 0.f, c = 0.f, d = 0.f;
        for (int w = 0; w < 4; ++w) { a += part[w][0]; b += part[w][1]; c += part[w][2]; d += part[w][3]; }
        atomicAdd(&acc[3], a); atomicAdd(&acc[4], b); atomicAdd(&acc[5], c); atomicAdd(&acc[6], d);
    }
}

__global__ void k_final(const float* __restrict__ acc, float* __restrict__ out, int B) {
    if (threadIdx.x == 0 && blockIdx.x == 0) {
        float invB = 1.f / (float)B;
        out[0] = -acc[0] * invB;
        out[1] = -0.1f * acc[1] * invB;
        out[2] = -0.1f * acc[2] * invB;
        float disc = acc[3] / (fmaxf(acc[4], 1.f) * 64.f) + acc[5] / (fmaxf(acc[6], 1.f) * 64.f);
        out[3] = -0.01f * disc;
    }
}

extern "C" void kernel_launch(void* const* d_in, const int* in_sizes, int n_in,
                              void* d_out, int out_size, void* d_ws, size_t ws_size,
                              hipStream_t stream) {
    const float* emb_int = (const float*)d_in[0];
    const float* emb_pop = (const float*)d_in[1];
    const int* user   = (const int*)d_in[2];
    const int* item_p = (const int*)d_in[3];
    const int* item_n = (const int*)d_in[4];
    const void* mask  = d_in[5];
    const int* src    = (const int*)d_in[6];
    const int* dst    = (const int*)d_in[7];

    const int D = 64;
    const int N = in_sizes[0] / D;   // 150000
    const int B = in_sizes[2];       // 4096
    const int E = in_sizes[6];       // 4000000
    const int NUSER = 100000;
    const int nb = (N + KNODES - 1) >> KSHIFT;   // 293

    char* ws = (char*)d_ws;
    size_t off = 0;
    auto take = [&](size_t bytes) -> void* {
        void* p = ws + off;
        off += (bytes + 255) & ~(size_t)255;
        return p;
    };
    float* acc      = (float*)take(256);            // acc[0..6]; flag at acc[15]
    float* item_ind = (float*)take((size_t)N * 4);
    float* user_ind = (float*)take((size_t)N * 4);
    u32*   bcnt     = (u32*)take((size_t)nb * 4);
    size_t zero_bytes = off;                         // region zeroed each call
    u32*   bstart   = (u32*)take((size_t)(nb + 1) * 4);
    u32*   bfill    = (u32*)take((size_t)nb * 4);
    u32*   rowstart = (u32*)take((size_t)(N + 1) * 4);
    float* norm     = (float*)take((size_t)N * 4);
    float* norm2    = (float*)take((size_t)N * 4);
    float* snorm    = (float*)take((size_t)N * 4);
    int*   csr      = (int*)take((size_t)E * 4);
    u32*   T0       = (u32*)take((size_t)N * D * 4);
    u32*   T1       = (u32*)take((size_t)N * D * 4);
    u32*   T2       = (u32*)take((size_t)N * D * 4);
    u32*   packed   = (u32*)T2;      // alias: packed dead before T2 is written
    int* flag = (int*)acc + 15;

    hipMemsetAsync(d_ws, 0, zero_bytes, stream);

    k_bhist<<<512, 256, 0, stream>>>(dst, bcnt, E, nb);
    k_bscan<<<1, 512, 0, stream>>>(bcnt, bstart, bfill, nb, (u32)E, rowstart, N);
    k_bscatter<<<(E + CHUNK - 1) / CHUNK, 256, 0, stream>>>(src, dst, bfill, packed, E, nb);
    k_bbuild<<<nb, 256, 0, stream>>>(packed, bstart, rowstart, norm, norm2, snorm, csr, N);
    k_pack<<<2048, 256, 0, stream>>>(emb_int, emb_pop, norm, T0, N);
    k_mask_detect<<<1, 256, 0, stream>>>((const int*)mask, flag);

    // layer 1: T1 = norm^2 .* (A T0)
    k_pull<<<2048, 256, 0, stream>>>(T0, T1, csr, rowstart, norm2, N);
    // layer 2: T2 = norm^2 .* (A T1)
    k_pull<<<2048, 256, 0, stream>>>(T1, T2, csr, rowstart, norm2, N);

    k_ind<<<64, 256, 0, stream>>>(user, item_p, item_n, item_ind, user_ind, B, NUSER);
    k_loss<<<(B * 64 + 255) / 256, 256, 0, stream>>>(emb_int, emb_pop, T1, T2, snorm,
                                                     user, item_p, item_n, mask, flag, acc, B, NUSER);
    k_disc<<<512, 256, 0, stream>>>(emb_int, emb_pop, T1, T2, snorm,
                                    item_ind, user_ind, acc, N);
    k_final<<<1, 64, 0, stream>>>(acc, (float*)d_out, B);
}

// Round 6
// 377.818 us; speedup vs baseline: 3.2986x; 1.3800x over previous
//
#include <hip/hip_runtime.h>
#include <hip/hip_bf16.h>

typedef unsigned int u32;
typedef float f32x2 __attribute__((ext_vector_type(2)));

#define KNODES 512
#define KSHIFT 9
#define NBMAX 1024
#define CHUNK 4096

__device__ __forceinline__ float log_sigmoid(float x) {
    return fminf(x, 0.f) - log1pf(expf(-fabsf(x)));
}

// fp8 e4m3 (hardware) pack/unpack: u32 holds 4 fp8 values; selector must be constexpr
template <bool HI>
__device__ __forceinline__ f32x2 up8(u32 v) {
    return __builtin_amdgcn_cvt_pk_f32_fp8(v, HI);
}
template <bool HI>
__device__ __forceinline__ u32 pk8(u32 old, float a, float b) {
    return __builtin_amdgcn_cvt_pk_fp8_f32(a, b, old, HI);
}

// ---------------- bucket histogram (buckets of 512 nodes) ----------------
__global__ void k_bhist(const int* __restrict__ dst, u32* __restrict__ bcnt, int E, int nb) {
    __shared__ u32 h[NBMAX];
    for (int i = threadIdx.x; i < nb; i += blockDim.x) h[i] = 0;
    __syncthreads();
    int stride = gridDim.x * blockDim.x;
    for (int e = blockIdx.x * blockDim.x + threadIdx.x; e < E; e += stride)
        atomicAdd(&h[((u32)dst[e]) >> KSHIFT], 1u);
    __syncthreads();
    for (int i = threadIdx.x; i < nb; i += blockDim.x)
        if (h[i]) atomicAdd(&bcnt[i], h[i]);
}

// ---------------- bucket scan (parallel, one block) ----------------
__global__ void k_bscan(const u32* __restrict__ bcnt, u32* __restrict__ bstart,
                        u32* __restrict__ bfill, int nb, u32 E,
                        u32* __restrict__ rowstart, int N) {
    __shared__ u32 lds[512];
    int t = threadIdx.x;
    u32 v = (t < nb) ? bcnt[t] : 0u;
    lds[t] = v;
    __syncthreads();
    for (int off = 1; off < 512; off <<= 1) {
        u32 x = (t >= off) ? lds[t - off] : 0u;
        __syncthreads();
        lds[t] += x;
        __syncthreads();
    }
    u32 incl = lds[t];
    u32 excl = incl - v;
    if (t < nb) { bstart[t] = excl; bfill[t] = excl; }
    if (t == nb - 1) bstart[nb] = incl;
    if (t == 0) rowstart[N] = E;
}

// ---------------- scatter edges into bucket-contiguous packed array ----------------
// pack = (local_dst[9b] << 18) | src[18b]
__global__ void k_bscatter(const int* __restrict__ src, const int* __restrict__ dst,
                           u32* __restrict__ bfill, u32* __restrict__ packed, int E, int nb) {
    __shared__ u32 h[NBMAX];
    const int t = threadIdx.x;
    const int base = blockIdx.x * CHUNK;
    const int PT = CHUNK / 256; // 16
    u32 dv[PT], sv[PT];
#pragma unroll
    for (int i = 0; i < PT; ++i) {
        int e = base + t + i * 256;
        if (e < E) { dv[i] = (u32)dst[e]; sv[i] = (u32)src[e]; }
        else dv[i] = 0xFFFFFFFFu;
    }
    for (int i = t; i < nb; i += 256) h[i] = 0;
    __syncthreads();
#pragma unroll
    for (int i = 0; i < PT; ++i)
        if (dv[i] != 0xFFFFFFFFu) atomicAdd(&h[dv[i] >> KSHIFT], 1u);
    __syncthreads();
    for (int i = t; i < nb; i += 256) {
        u32 c = h[i];
        h[i] = c ? atomicAdd(&bfill[i], c) : 0u;
    }
    __syncthreads();
#pragma unroll
    for (int i = 0; i < PT; ++i) {
        if (dv[i] != 0xFFFFFFFFu) {
            u32 b = dv[i] >> KSHIFT;
            u32 pos = atomicAdd(&h[b], 1u);
            packed[pos] = ((dv[i] & (KNODES - 1)) << 18) | sv[i];
        }
    }
}

// ---------------- per-bucket CSR build: deg, rowstart, norms, csr ----------------
__global__ void k_bbuild(const u32* __restrict__ packed, const u32* __restrict__ bstart,
                         u32* __restrict__ rowstart, float* __restrict__ norm,
                         float* __restrict__ norm2, float* __restrict__ snorm,
                         int* __restrict__ csr, int N) {
    __shared__ u32 deg[KNODES], fill[KNODES], s256[256];
    const int t = threadIdx.x;
    const int bkt = blockIdx.x;
    const int nodeBase = bkt << KSHIFT;
    u32 e0 = bstart[bkt], e1 = bstart[bkt + 1];
    deg[t] = 0; deg[t + 256] = 0;
    __syncthreads();
    for (u32 e = e0 + t; e < e1; e += 256)
        atomicAdd(&deg[packed[e] >> 18], 1u);
    __syncthreads();
    u32 a = deg[2 * t], b = deg[2 * t + 1];
    s256[t] = a + b;
    __syncthreads();
    for (int off = 1; off < 256; off <<= 1) {
        u32 x = (t >= off) ? s256[t - off] : 0u;
        __syncthreads();
        s256[t] += x;
        __syncthreads();
    }
    u32 ebase = (t ? s256[t - 1] : 0u);
    fill[2 * t] = ebase;
    fill[2 * t + 1] = ebase + a;
    int n0 = nodeBase + 2 * t, n1 = nodeBase + 2 * t + 1;
    if (n0 < N) {
        float da = fmaxf((float)a, 1.f);
        float nr = rsqrtf(da);
        rowstart[n0] = e0 + ebase; norm[n0] = nr; norm2[n0] = nr * nr;
        snorm[n0] = sqrtf(da) * (1.f / 64.f);
    }
    if (n1 < N) {
        float db = fmaxf((float)b, 1.f);
        float nr = rsqrtf(db);
        rowstart[n1] = e0 + ebase + a; norm[n1] = nr; norm2[n1] = nr * nr;
        snorm[n1] = sqrtf(db) * (1.f / 64.f);
    }
    __syncthreads();
    for (u32 e = e0 + t; e < e1; e += 256) {
        u32 p = packed[e];
        u32 ln = p >> 18;
        u32 pos = atomicAdd(&fill[ln], 1u);
        csr[e0 + pos] = (int)(p & 0x3FFFFu);
    }
}

// ---------------- pack: T0[n] = fp8(64 * norm[n] * emb); row = 32 u32 (I: 0-15, P: 16-31) ----------------
__global__ void k_pack(const float* __restrict__ eI, const float* __restrict__ eP,
                       const float* __restrict__ norm, u32* __restrict__ T0, int N) {
    int idx = blockIdx.x * blockDim.x + threadIdx.x;
    int total = N * 32;
    int stride = gridDim.x * blockDim.x;
    for (; idx < total; idx += stride) {
        int n = idx >> 5, k = idx & 31;
        const float* e = (k >= 16) ? eP : eI;
        int d0 = (4 * k) & 63;
        float4 v = *(const float4*)&e[(size_t)n * 64 + d0];
        float s = 64.f * norm[n];
        u32 w = 0;
        w = pk8<false>(w, v.x * s, v.y * s);
        w = pk8<true>(w, v.z * s, v.w * s);
        T0[idx] = w;
    }
}

// ---------------- mask dtype detection (bool-as-uint8 vs int32) ----------------
__global__ void k_mask_detect(const int* __restrict__ m, int* flag) {
    __shared__ int allok;
    if (threadIdx.x == 0) allok = 1;
    __syncthreads();
    bool ok = true;
    for (int i = threadIdx.x; i < 1024; i += blockDim.x) {
        int v = m[i];
        if (v != 0 && v != 1) ok = false;
    }
    if (!ok) allok = 0;
    __syncthreads();
    if (threadIdx.x == 0) flag[0] = allok;   // 1 => int32 mask, 0 => byte mask
}

// ---------------- propagation: wave per node, 4 edges/iter, fp8 rows (128B) ----------------
// lane = grp*16 + r: grp picks edge within quad, r picks 8B chunk of the 128B row.
#define ACC8(u) { f32x2 p0 = up8<false>(u.x), p1 = up8<true>(u.x); \
                  f32x2 p2 = up8<false>(u.y), p3 = up8<true>(u.y); \
                  a0 += p0.x; a1 += p0.y; a2 += p1.x; a3 += p1.y;  \
                  a4 += p2.x; a5 += p2.y; a6 += p3.x; a7 += p3.y; }

__global__ void k_pull(const u32* __restrict__ Tin, u32* __restrict__ Tout,
                       const int* __restrict__ csr, const u32* __restrict__ rowstart,
                       const float* __restrict__ norm2, int N) {
    int lane = threadIdx.x & 63;
    int grp = lane >> 4;     // 0..3
    int r = lane & 15;       // 0..15
    int wid = (blockIdx.x * blockDim.x + threadIdx.x) >> 6;
    int nw = (gridDim.x * blockDim.x) >> 6;
    for (int n = wid; n < N; n += nw) {
        u32 s0 = rowstart[n], s1 = rowstart[n + 1];
        float a0 = 0.f, a1 = 0.f, a2 = 0.f, a3 = 0.f, a4 = 0.f, a5 = 0.f, a6 = 0.f, a7 = 0.f;
        for (u32 e0 = s0; e0 < s1; e0 += 64) {
            int cnt = (int)min(64u, s1 - e0);
            int sidx = (lane < cnt) ? csr[e0 + lane] : 0;
            int j = 0;
            for (; j + 8 <= cnt; j += 8) {
                int sA = __shfl(sidx, j + grp);
                int sB = __shfl(sidx, j + 4 + grp);
                uint2 uA = *(const uint2*)&Tin[(size_t)sA * 32 + 2 * r];
                uint2 uB = *(const uint2*)&Tin[(size_t)sB * 32 + 2 * r];
                ACC8(uA); ACC8(uB);
            }
            for (; j + 4 <= cnt; j += 4) {
                int sA = __shfl(sidx, j + grp);
                uint2 uA = *(const uint2*)&Tin[(size_t)sA * 32 + 2 * r];
                ACC8(uA);
            }
            int rem = cnt - j;
            if (rem) {
                int jj = j + grp;
                int s = __shfl(sidx, (jj < cnt) ? jj : 0);
                if (grp < rem) {
                    uint2 u = *(const uint2*)&Tin[(size_t)s * 32 + 2 * r];
                    ACC8(u);
                }
            }
        }
        // merge the 4 edge-groups (lanes with equal r hold the same slots)
        a0 += __shfl_xor(a0, 16); a1 += __shfl_xor(a1, 16);
        a2 += __shfl_xor(a2, 16); a3 += __shfl_xor(a3, 16);
        a4 += __shfl_xor(a4, 16); a5 += __shfl_xor(a5, 16);
        a6 += __shfl_xor(a6, 16); a7 += __shfl_xor(a7, 16);
        a0 += __shfl_xor(a0, 32); a1 += __shfl_xor(a1, 32);
        a2 += __shfl_xor(a2, 32); a3 += __shfl_xor(a3, 32);
        a4 += __shfl_xor(a4, 32); a5 += __shfl_xor(a5, 32);
        a6 += __shfl_xor(a6, 32); a7 += __shfl_xor(a7, 32);
        float nn = norm2[n];
        if (lane < 16) {
            u32 w0 = 0, w1 = 0;
            w0 = pk8<false>(w0, a0 * nn, a1 * nn);
            w0 = pk8<true>(w0, a2 * nn, a3 * nn);
            w1 = pk8<false>(w1, a4 * nn, a5 * nn);
            w1 = pk8<true>(w1, a6 * nn, a7 * nn);
            uint2 w; w.x = w0; w.y = w1;
            *(uint2*)&Tout[(size_t)n * 32 + 2 * r] = w;
        }
    }
}

// ---------------- indicator build ----------------
__global__ void k_ind(const int* __restrict__ user, const int* __restrict__ itp,
                      const int* __restrict__ itn,
                      float* __restrict__ item_ind, float* __restrict__ user_ind,
                      int B, int NUSER) {
    int stride = gridDim.x * blockDim.x;
    for (int b = blockIdx.x * blockDim.x + threadIdx.x; b < B; b += stride) {
        item_ind[itp[b] + NUSER] = 1.f;
        item_ind[itn[b] + NUSER] = 1.f;
        user_ind[user[b]] = 1.f;
    }
}

// f dims (2lh, 2lh+1) of one table (toff = 0 for I, 16 for P) for row r
__device__ __forceinline__ void fval2(const float* __restrict__ eb,
                                      const u32* __restrict__ T1, const u32* __restrict__ T2,
                                      const float* __restrict__ snorm,
                                      int r, int toff, int lh, float& f0, float& f1) {
    float2 ev = *(const float2*)&eb[(size_t)r * 64 + 2 * lh];
    u32 w1 = T1[(size_t)r * 32 + toff + (lh >> 1)];
    u32 w2 = T2[(size_t)r * 32 + toff + (lh >> 1)];
    bool hi = lh & 1;
    f32x2 t1 = hi ? up8<true>(w1) : up8<false>(w1);
    f32x2 t2 = hi ? up8<true>(w2) : up8<false>(w2);
    float sr = snorm[r];   // sqrt(deg)/64
    f0 = (ev.x + sr * (t1.x + t2.x)) * (1.f / 3.f);
    f1 = (ev.y + sr * (t1.y + t2.y)) * (1.f / 3.f);
}

// ---------------- batched losses: wave per batch row ----------------
__global__ void k_loss(const float* __restrict__ eI, const float* __restrict__ eP,
                       const u32* __restrict__ T1, const u32* __restrict__ T2,
                       const float* __restrict__ snorm,
                       const int* __restrict__ user, const int* __restrict__ itp, const int* __restrict__ itn,
                       const void* __restrict__ maskp, const int* __restrict__ flag,
                       float* __restrict__ acc, int B, int NUSER) {
    int lane = threadIdx.x & 63;
    int wib = threadIdx.x >> 6;
    int b = (blockIdx.x * blockDim.x + threadIdx.x) >> 6;
    __shared__ float part[4][3];
    float r0 = 0.f, r1 = 0.f, r2 = 0.f;
    if (b < B) {
        int u = user[b];
        int ip = itp[b] + NUSER;
        int in_ = itn[b] + NUSER;
        int half = lane >> 5, lh = lane & 31;
        int toff = half ? 16 : 0;
        const float* eb = half ? eP : eI;
        float u0, u1, p0, p1, n0, n1;
        fval2(eb, T1, T2, snorm, u,   toff, lh, u0, u1);
        fval2(eb, T1, T2, snorm, ip,  toff, lh, p0, p1);
        fval2(eb, T1, T2, snorm, in_, toff, lh, n0, n1);
        float dp = u0 * p0 + u1 * p1;
        float dn = u0 * n0 + u1 * n1;
        for (int off = 1; off < 32; off <<= 1) {
            dp += __shfl_xor(dp, off);
            dn += __shfl_xor(dn, off);
        }
        float dpI = __shfl(dp, 0), dpP = __shfl(dp, 32);
        float dnI = __shfl(dn, 0), dnP = __shfl(dn, 32);
        if (lane == 0) {
            float m = (*flag) ? (float)(((const int*)maskp)[b] != 0)
                              : (float)(((const unsigned char*)maskp)[b] != 0);
            r0 = log_sigmoid(dpI + dpP - dnI - dnP);
            r1 = m * log_sigmoid(dpI - dnI);
            r2 = m * log_sigmoid(dnP - dpP) + (1.f - m) * log_sigmoid(dpP - dnP);
        }
    }
    if (lane == 0) { part[wib][0] = r0; part[wib][1] = r1; part[wib][2] = r2; }
    __syncthreads();
    if (threadIdx.x == 0) {
        float s0 = 0.f, s1 = 0.f, s2 = 0.f;
        for (int w = 0; w < 4; ++w) { s0 += part[w][0]; s1 += part[w][1]; s2 += part[w][2]; }
        atomicAdd(&acc[0], s0); atomicAdd(&acc[1], s1); atomicAdd(&acc[2], s2);
    }
}

// ---------------- discrepancy: wave per node, skip non-indicated rows ----------------
__global__ void k_disc(const float* __restrict__ eI, const float* __restrict__ eP,
                       const u32* __restrict__ T1, const u32* __restrict__ T2,
                       const float* __restrict__ snorm,
                       const float* __restrict__ item_ind, const float* __restrict__ user_ind,
                       float* __restrict__ acc, int N) {
    int lane = threadIdx.x & 63;
    int wib = threadIdx.x >> 6;
    int wid = (blockIdx.x * blockDim.x + threadIdx.x) >> 6;
    int nw = (gridDim.x * blockDim.x) >> 6;
    int half = lane >> 5, lh = lane & 31;
    int toff = half ? 16 : 0;
    const float* eb = half ? eP : eI;
    float sI = 0.f, sU = 0.f, cI = 0.f, cU = 0.f;
    for (int n = wid; n < N; n += nw) {
        float ii = item_ind[n], ui = user_ind[n];
        if (ii + ui == 0.f) continue;      // wave-uniform: all lanes share n
        float f0, f1;
        fval2(eb, T1, T2, snorm, n, toff, lh, f0, f1);
        float o0 = __shfl_xor(f0, 32), o1 = __shfl_xor(f1, 32);
        float d0 = f0 - o0, d1 = f1 - o1;
        float dd = d0 * d0 + d1 * d1;      // identical in both halves (double count)
        sI += ii * dd; sU += ui * dd;
        if (lane == 0) { cI += ii; cU += ui; }
    }
    for (int off = 1; off < 64; off <<= 1) { sI += __shfl_xor(sI, off); sU += __shfl_xor(sU, off); }
    __shared__ float part[4][4];
    if (lane == 0) { part[wib][0] = 0.5f * sI; part[wib][1] = cI; part[wib][2] = 0.5f * sU; part[wib][3] = cU; }
    __syncthreads();
    if (threadIdx.x == 0) {
        float a = 0.f, b = 0.f, c = 0.f, d = 0.f;
        for (int w = 0; w < 4; ++w) { a += part[w][0]; b += part[w][1]; c += part[w][2]; d += part[w][3]; }
        atomicAdd(&acc[3], a); atomicAdd(&acc[4], b); atomicAdd(&acc[5], c); atomicAdd(&acc[6], d);
    }
}

__global__ void k_final(const float* __restrict__ acc, float* __restrict__ out, int B) {
    if (threadIdx.x == 0 && blockIdx.x == 0) {
        float invB = 1.f / (float)B;
        out[0] = -acc[0] * invB;
        out[1] = -0.1f * acc[1] * invB;
        out[2] = -0.1f * acc[2] * invB;
        float disc = acc[3] / (fmaxf(acc[4], 1.f) * 64.f) + acc[5] / (fmaxf(acc[6], 1.f) * 64.f);
        out[3] = -0.01f * disc;
    }
}

extern "C" void kernel_launch(void* const* d_in, const int* in_sizes, int n_in,
                              void* d_out, int out_size, void* d_ws, size_t ws_size,
                              hipStream_t stream) {
    const float* emb_int = (const float*)d_in[0];
    const float* emb_pop = (const float*)d_in[1];
    const int* user   = (const int*)d_in[2];
    const int* item_p = (const int*)d_in[3];
    const int* item_n = (const int*)d_in[4];
    const void* mask  = d_in[5];
    const int* src    = (const int*)d_in[6];
    const int* dst    = (const int*)d_in[7];

    const int D = 64;
    const int N = in_sizes[0] / D;   // 150000
    const int B = in_sizes[2];       // 4096
    const int E = in_sizes[6];       // 4000000
    const int NUSER = 100000;
    const int nb = (N + KNODES - 1) >> KSHIFT;   // 293

    char* ws = (char*)d_ws;
    size_t off = 0;
    auto take = [&](size_t bytes) -> void* {
        void* p = ws + off;
        off += (bytes + 255) & ~(size_t)255;
        return p;
    };
    float* acc      = (float*)take(256);            // acc[0..6]; flag at acc[15]
    float* item_ind = (float*)take((size_t)N * 4);
    float* user_ind = (float*)take((size_t)N * 4);
    u32*   bcnt     = (u32*)take((size_t)nb * 4);
    size_t zero_bytes = off;                         // region zeroed each call
    u32*   bstart   = (u32*)take((size_t)(nb + 1) * 4);
    u32*   bfill    = (u32*)take((size_t)nb * 4);
    u32*   rowstart = (u32*)take((size_t)(N + 1) * 4);
    float* norm     = (float*)take((size_t)N * 4);
    float* norm2    = (float*)take((size_t)N * 4);
    float* snorm    = (float*)take((size_t)N * 4);
    int*   csr      = (int*)take((size_t)E * 4);
    u32*   T0       = (u32*)take((size_t)N * 32 * 4);
    u32*   T1       = (u32*)take((size_t)N * 32 * 4);
    u32*   T2       = (u32*)take((size_t)N * 32 * 4);
    u32*   packed   = (u32*)T2;      // alias: packed dead before T2 is written
    int* flag = (int*)acc + 15;

    (void)hipMemsetAsync(d_ws, 0, zero_bytes, stream);

    k_bhist<<<512, 256, 0, stream>>>(dst, bcnt, E, nb);
    k_bscan<<<1, 512, 0, stream>>>(bcnt, bstart, bfill, nb, (u32)E, rowstart, N);
    k_bscatter<<<(E + CHUNK - 1) / CHUNK, 256, 0, stream>>>(src, dst, bfill, packed, E, nb);
    k_bbuild<<<nb, 256, 0, stream>>>(packed, bstart, rowstart, norm, norm2, snorm, csr, N);
    k_pack<<<2048, 256, 0, stream>>>(emb_int, emb_pop, norm, T0, N);
    k_mask_detect<<<1, 256, 0, stream>>>((const int*)mask, flag);

    // layer 1: T1 = norm^2 .* (A T0)
    k_pull<<<2048, 256, 0, stream>>>(T0, T1, csr, rowstart, norm2, N);
    // layer 2: T2 = norm^2 .* (A T1)
    k_pull<<<2048, 256, 0, stream>>>(T1, T2, csr, rowstart, norm2, N);

    k_ind<<<64, 256, 0, stream>>>(user, item_p, item_n, item_ind, user_ind, B, NUSER);
    k_loss<<<(B * 64 + 255) / 256, 256, 0, stream>>>(emb_int, emb_pop, T1, T2, snorm,
                                                     user, item_p, item_n, mask, flag, acc, B, NUSER);
    k_disc<<<512, 256, 0, stream>>>(emb_int, emb_pop, T1, T2, snorm,
                                    item_ind, user_ind, acc, N);
    k_final<<<1, 64, 0, stream>>>(acc, (float*)d_out, B);
}